// Round 16
// baseline (243.027 us; speedup 1.0000x reference)
//
#include <hip/hip_runtime.h>
#include <hip/hip_fp16.h>
#include <math.h>

#define T_SEQ 1152

typedef _Float16 f16x8 __attribute__((ext_vector_type(8)));
typedef float f32x4 __attribute__((ext_vector_type(4)));

// ---------------------------------------------------------------------------
// Kernel 0: M[b,m,s] = sum_n spatial_w[n,s] * L_norm[b,n,m]  ([b][m][s] layout)
// ---------------------------------------------------------------------------
__global__ void mKernel(const float* __restrict__ L, const float* __restrict__ sw,
                        float* __restrict__ Mbuf) {
  int b = blockIdx.x, tid = threadIdx.x;   // 256 threads
  int s = tid >> 6, m = tid & 63;
  float a = 0.f;
  #pragma unroll 4
  for (int n = 0; n < 64; ++n)
    a = fmaf(sw[n * 4 + s], L[(b * 64 + n) * 64 + m], a);
  Mbuf[b * 256 + m * 4 + s] = a;
}

// ---------------------------------------------------------------------------
// Kernel A v16: t-tile 32 -> 2304 blocks (2x grid) so ~9 blocks/CU nominal,
// up to 32 waves/CU co-resident (v13/v15 were grid-starved at 4.5 blocks/CU).
// Same verified GEMM: A = K (16 rows = 8f x {t,t+16} kh-shift), B = X
// (16 cols), K-dim 384 = 12 MFMA of K=32. Each of the 4 waves covers the
// FULL 32-t tile and 2 channels per part (4 waves x 2 = 8 c2/part).
// Per part: stage (63 rows x 8 c2, stride 65) -> B1 -> per wave {2x(12 MFMA
// -> hT4)} -> per-thread LN+proj (1 point/lane) -> B2. LDS ~16.5 KB.
// Epilogue: shfl_xor(1) c-pair merge + 2-pass cross-wave sum via hT4 region.
// ---------------------------------------------------------------------------
__global__ __launch_bounds__(256, 4)
void convKernel(const float* __restrict__ X, const float* __restrict__ Kw,
                const float* __restrict__ lnS, const float* __restrict__ lnB,
                const float* __restrict__ Mbuf, float* __restrict__ snn) {
  __shared__ int4   XS[8 * 65];       // [c2][row<63] fp16x8 rows; 8320 B
  __shared__ float4 hT4[512];         // [wid][cp][fq][tloc]; 8192 B; RedF alias

  const int bid  = blockIdx.x;        // 0..2303
  const int b    = bid / 36;
  const int tile = bid - b * 36;      // 0..35
  const int t0   = tile * 32;
  const int tid  = threadIdx.x;       // 0..255
  const int lane = tid & 63;
  const int wid  = tid >> 6;          // 0..3
  const int tcol = lane & 15;         // B col = local t
  const int rg   = lane >> 4;         // k-group; C/D rows rg*4+r
  const int fq   = rg & 1;            // f-quad of this lane's C/D rows
  const int tloc = tcol + ((rg >> 1) << 4);   // C/D local t (0..31)

  // ---- A-frags (K): rows 0-7 = f0-7 @ t, rows 8-15 = f0-7 @ t+16
  const int rA = lane & 15;
  const int fr = rA & 7;
  const int sh16 = (rA >> 3) << 4;
  f16x8 ka[12];
  #pragma unroll
  for (int q = 0; q < 12; ++q) {
    const int khs = 4 * q + rg - sh16;
    #pragma unroll
    for (int j = 0; j < 8; ++j) {
      float kv = (khs >= 0 && khs < 32) ? Kw[khs * 64 + j * 8 + fr] : 0.f;
      ka[q][j] = (_Float16)kv;
    }
  }

  // ---- per-thread LN/proj ids: 1 point (tpt, c2l=cslot) per part
  const int tpt   = lane >> 1;        // local t 0..31
  const int cslot = lane & 1;         // which of my wave's 2 channels

  // ---- staging geometry: 504 slots = 8 c2 x 63 rows; 2 per thread
  const int sc2 = tid & 7;
  const int srow0 = tid >> 3;         // 0..31
  const int srow1 = srow0 + 32;       // 32..63 (63 invalid)
  const int st0 = t0 - 15 + srow0;
  const int st1 = t0 - 15 + srow1;
  const bool v0 = (st0 >= 0) && (st0 < T_SEQ);
  const bool v1 = (srow1 < 63) && (st1 >= 0) && (st1 < T_SEQ);
  const float* xb = X + (size_t)(b * T_SEQ) * 512;

  float pacc[4][8];
  #pragma unroll
  for (int s = 0; s < 4; ++s)
    #pragma unroll
    for (int f = 0; f < 8; ++f) pacc[s][f] = 0.f;

  #pragma unroll 1
  for (int part = 0; part < 8; ++part) {
    // ---- stage X rows -> fp16 XS (direct)
    {
      const float* xp = xb + (part * 8 + sc2) * 8;
      float4 a0 = make_float4(0.f, 0.f, 0.f, 0.f), a1 = a0;
      float4 b0 = a0, b1 = a0;
      if (v0) { const float* p = xp + (size_t)st0 * 512; a0 = *(const float4*)p; a1 = *(const float4*)(p + 4); }
      if (v1) { const float* p = xp + (size_t)st1 * 512; b0 = *(const float4*)p; b1 = *(const float4*)(p + 4); }
      {
        unsigned u0 = __builtin_bit_cast(unsigned, __float22half2_rn(make_float2(a0.x, a0.y)));
        unsigned u1 = __builtin_bit_cast(unsigned, __float22half2_rn(make_float2(a0.z, a0.w)));
        unsigned u2 = __builtin_bit_cast(unsigned, __float22half2_rn(make_float2(a1.x, a1.y)));
        unsigned u3 = __builtin_bit_cast(unsigned, __float22half2_rn(make_float2(a1.z, a1.w)));
        int4 v; v.x = (int)u0; v.y = (int)u1; v.z = (int)u2; v.w = (int)u3;
        XS[sc2 * 65 + srow0] = v;
      }
      if (srow1 < 63) {
        unsigned u0 = __builtin_bit_cast(unsigned, __float22half2_rn(make_float2(b0.x, b0.y)));
        unsigned u1 = __builtin_bit_cast(unsigned, __float22half2_rn(make_float2(b0.z, b0.w)));
        unsigned u2 = __builtin_bit_cast(unsigned, __float22half2_rn(make_float2(b1.x, b1.y)));
        unsigned u3 = __builtin_bit_cast(unsigned, __float22half2_rn(make_float2(b1.z, b1.w)));
        int4 v; v.x = (int)u0; v.y = (int)u1; v.z = (int)u2; v.w = (int)u3;
        XS[sc2 * 65 + srow1] = v;
      }
    }
    __syncthreads();   // B1: XS ready

    // ---- MFMA: this wave's 2 c2; acc -> hT4 (wave-private, conflict-free)
    #pragma unroll
    for (int cp = 0; cp < 2; ++cp) {
      f32x4 acc = {0.f, 0.f, 0.f, 0.f};
      const int rb = (wid * 2 + cp) * 65 + tcol + rg;
      #pragma unroll
      for (int q = 0; q < 12; ++q) {
        f16x8 xf = __builtin_bit_cast(f16x8, XS[rb + 4 * q]);
        acc = __builtin_amdgcn_mfma_f32_16x16x32_f16(ka[q], xf, acc, 0, 0, 0);
      }
      float4 st; st.x = acc[0]; st.y = acc[1]; st.z = acc[2]; st.w = acc[3];
      hT4[wid * 128 + cp * 64 + fq * 32 + tloc] = st;
    }
    // wave-local lgkmcnt orders hT4 writes vs reads (compiler-inserted)

    // ---- per-thread LN + ReLU + proj: 1 point (tpt, cslot)
    {
      float4 lo = hT4[wid * 128 + cslot * 64 + tpt];
      float4 hi = hT4[wid * 128 + cslot * 64 + 32 + tpt];
      float hv[8] = { lo.x, lo.y, lo.z, lo.w, hi.x, hi.y, hi.z, hi.w };
      float mu = 0.f;
      #pragma unroll
      for (int f = 0; f < 8; ++f) mu += hv[f];
      mu *= 0.125f;
      float var = 0.f;
      #pragma unroll
      for (int f = 0; f < 8; ++f) { float d = hv[f] - mu; hv[f] = d; var = fmaf(d, d, var); }
      float rs = 1.0f / sqrtf(var * 0.125f + 1e-6f);
      const int c = part * 8 + wid * 2 + cslot;
      const float4 Mc = *(const float4*)(Mbuf + b * 256 + c * 4);
      #pragma unroll
      for (int f = 0; f < 8; ++f) {
        float hh = fmaxf(fmaf(hv[f] * rs, lnS[f], lnB[f]), 0.f);
        pacc[0][f] = fmaf(hh, Mc.x, pacc[0][f]);
        pacc[1][f] = fmaf(hh, Mc.y, pacc[1][f]);
        pacc[2][f] = fmaf(hh, Mc.z, pacc[2][f]);
        pacc[3][f] = fmaf(hh, Mc.w, pacc[3][f]);
      }
    }
    __syncthreads();   // B2: all XS/hT4 reads done before next part
  }

  // ---- epilogue: merge this wave's 2 channels (lane pairs), then 2-pass
  //      cross-wave sum through the hT4 region (2048 floats).
  #pragma unroll
  for (int s = 0; s < 4; ++s)
    #pragma unroll
    for (int f = 0; f < 8; ++f)
      pacc[s][f] += __shfl_xor(pacc[s][f], 1, 64);

  float* R = (float*)hT4;             // 2048 floats; per pass uses 1536
  #pragma unroll 1
  for (int pass = 0; pass < 2; ++pass) {
    __syncthreads();                  // prev-pass reads (or main loop) done
    if (wid > 0 && cslot == 0) {
      #pragma unroll
      for (int s2 = 0; s2 < 2; ++s2)
        #pragma unroll
        for (int f = 0; f < 8; ++f)
          R[((wid - 1) * 32 + tpt) * 16 + s2 * 8 + f] = pacc[pass * 2 + s2][f];
    }
    __syncthreads();
    if (wid == 0 && cslot == 0) {
      float* op = snn + ((size_t)b * T_SEQ + t0 + tpt) * 32;
      #pragma unroll
      for (int s2 = 0; s2 < 2; ++s2) {
        const int s = pass * 2 + s2;
        float v[8];
        #pragma unroll
        for (int f = 0; f < 8; ++f)
          v[f] = pacc[s][f]
               + R[(0 * 32 + tpt) * 16 + s2 * 8 + f]
               + R[(1 * 32 + tpt) * 16 + s2 * 8 + f]
               + R[(2 * 32 + tpt) * 16 + s2 * 8 + f];
        *(float4*)(op + s * 8)     = make_float4(v[0], v[1], v[2], v[3]);
        *(float4*)(op + s * 8 + 4) = make_float4(v[4], v[5], v[6], v[7]);
      }
    }
  }
}

// ---------------------------------------------------------------------------
// Kernel B: LIF scan — 1 chain/thread (32 blocks x 64 thr = 2048 chains),
// 24-deep ping-pong prefetch.
// ---------------------------------------------------------------------------
__global__ __launch_bounds__(64, 1)
void scanKernel(const float* __restrict__ snn, float* __restrict__ flat,
                float* __restrict__ spkPart) {
  const int tid = threadIdx.x;        // 0..63
  const int j = tid & 31;
  const int b = blockIdx.x * 2 + (tid >> 5);
  const float* base = snn + (size_t)b * T_SEQ * 32 + j;

  float m1 = 0.f, m2 = 0.f, mo = 0.f, s1 = 0.f, s2 = 0.f;
  float cur[24], nxt[24];
  #pragma unroll
  for (int u = 0; u < 24; ++u) cur[u] = base[(size_t)u * 32];

  #pragma unroll 1
  for (int ch = 0; ch < 48; ++ch) {
    if (ch < 47) {
      #pragma unroll
      for (int u = 0; u < 24; ++u) nxt[u] = base[(size_t)((ch + 1) * 24 + u) * 32];
    }
    float aS = 0.f, aE = 0.f;
    #pragma unroll
    for (int u = 0; u < 24; ++u) {
      m1 = m1 * 0.8f + cur[u];
      float sp1 = (m1 > 0.5f) ? 1.f : 0.f;  m1 -= sp1 * 0.5f;
      m2 = m2 * 0.9f + sp1;
      float sp2 = (m2 > 0.5f) ? 1.f : 0.f;  m2 -= sp2 * 0.5f;
      mo = mo * 0.95f + sp2;
      s1 += sp1; s2 += sp2;
      if (u < 12) aS += mo; else aE += mo;
    }
    flat[b * 3072 + ch * 64 + j]      = aS / 12.0f;
    flat[b * 3072 + ch * 64 + 32 + j] = aE / 12.0f;
    if (ch < 47) {
      #pragma unroll
      for (int u = 0; u < 24; ++u) cur[u] = nxt[u];
    }
  }
  for (int off = 16; off > 0; off >>= 1) {
    s1 += __shfl_down(s1, off, 32);
    s2 += __shfl_down(s2, off, 32);
  }
  if (j == 0) { spkPart[b * 2] = s1; spkPart[b * 2 + 1] = s2; }
}

// ---------------------------------------------------------------------------
// Kernel C: y = gelu(flat @ W1 + b1); logits = y @ W2 + b2 ; firing rate.
// ---------------------------------------------------------------------------
__global__ void mlpKernel(const float* __restrict__ flat, const float* __restrict__ W1,
                          const float* __restrict__ b1, const float* __restrict__ W2,
                          const float* __restrict__ b2, const float* __restrict__ spkPart,
                          float* __restrict__ out) {
  if (blockIdx.x == 64) {
    if (threadIdx.x == 0) {
      float s1 = 0.f, s2 = 0.f;
      for (int i = 0; i < 64; ++i) { s1 += spkPart[2*i]; s2 += spkPart[2*i+1]; }
      out[256] = (s1 + s2) * 0.5f / (64.0f * 1152.0f * 32.0f);
    }
    return;
  }
  const int b = blockIdx.x;
  const int tid = threadIdx.x;        // 256
  const int u = tid & 31, kc = tid >> 5;
  __shared__ float red[256];
  __shared__ float ys[32];
  float p = 0.f;
  const int kbeg = kc * 384, kend = kbeg + 384;
  #pragma unroll 4
  for (int k = kbeg; k < kend; ++k)
    p = fmaf(flat[b*3072 + k], W1[k*32 + u], p);
  red[tid] = p;
  __syncthreads();
  if (kc == 0) {
    float y = b1[u];
    #pragma unroll
    for (int q = 0; q < 8; ++q) y += red[q*32 + u];
    float y3 = y * y * y;
    float th = tanhf(0.7978845608028654f * (y + 0.044715f * y3));
    ys[u] = 0.5f * y * (1.0f + th);
  }
  __syncthreads();
  if (tid < 4) {
    float accv = b2[tid];
    #pragma unroll
    for (int q = 0; q < 32; ++q) accv = fmaf(ys[q], W2[q*4 + tid], accv);
    out[b*4 + tid] = accv;
  }
}

// ---------------------------------------------------------------------------
extern "C" void kernel_launch(void* const* d_in, const int* in_sizes, int n_in,
                              void* d_out, int out_size, void* d_ws, size_t ws_size,
                              hipStream_t stream) {
  const float* L   = (const float*)d_in[0];
  const float* X   = (const float*)d_in[1];
  // d_in[2] = deterministic (unused)
  const float* Kw  = (const float*)d_in[3];
  const float* lnS = (const float*)d_in[4];
  const float* lnB = (const float*)d_in[5];
  const float* sw  = (const float*)d_in[6];
  const float* W1  = (const float*)d_in[7];
  const float* b1  = (const float*)d_in[8];
  const float* W2  = (const float*)d_in[9];
  const float* b2  = (const float*)d_in[10];

  float* ws   = (float*)d_ws;
  float* Mbuf = ws;                       // 64*4*64    = 16384
  float* snn  = Mbuf + 16384;             // 64*1152*32 = 2359296
  float* flat = snn + 2359296;            // 64*3072    = 196608
  float* spk  = flat + 196608;            // 128
  float* out  = (float*)d_out;

  mKernel<<<64, 256, 0, stream>>>(L, sw, Mbuf);
  convKernel<<<2304, 256, 0, stream>>>(X, Kw, lnS, lnB, Mbuf, snn);
  scanKernel<<<32, 64, 0, stream>>>(snn, flat, spk);
  mlpKernel<<<65, 256, 0, stream>>>(flat, W1, b1, W2, b2, spk, out);
}

// Round 17
// 149.775 us; speedup vs baseline: 1.6226x; 1.6226x over previous
//
#include <hip/hip_runtime.h>
#include <hip/hip_fp16.h>
#include <math.h>

#define T_SEQ 1152

typedef _Float16 f16x8 __attribute__((ext_vector_type(8)));
typedef float f32x4 __attribute__((ext_vector_type(4)));

// ---------------------------------------------------------------------------
// Kernel 0: M[b,m,s] = sum_n spatial_w[n,s] * L_norm[b,n,m]  ([b][m][s] layout)
// ---------------------------------------------------------------------------
__global__ void mKernel(const float* __restrict__ L, const float* __restrict__ sw,
                        float* __restrict__ Mbuf) {
  int b = blockIdx.x, tid = threadIdx.x;   // 256 threads
  int s = tid >> 6, m = tid & 63;
  float a = 0.f;
  #pragma unroll 4
  for (int n = 0; n < 64; ++n)
    a = fmaf(sw[n * 4 + s], L[(b * 64 + n) * 64 + m], a);
  Mbuf[b * 256 + m * 4 + s] = a;
}

// ---------------------------------------------------------------------------
// Kernel A v17 = v16 with the epilogue pass-loop FULLY UNROLLED (v16's
// `#pragma unroll 1` made pacc[pass*2+s2] runtime-indexed -> the whole
// accumulator spilled to scratch: WRITE_SIZE 571MB, 2x regression).
// t-tile 32 -> 2304 blocks; 4 waves each cover the full 32-t tile, 2 c2/wave
// per part. GEMM: A = K (16 rows = 8f x {t,t+16}), B = X (16 cols), 12 MFMA.
// Per part: stage (63 rows x 8 c2, stride 65) -> B1 -> {2x(12 MFMA -> hT4)}
// -> per-thread LN+proj (1 point/lane) -> B2. LDS ~16.5 KB.
// Epilogue: shfl_xor(1) c-pair merge + 2-pass (unrolled) cross-wave sum.
// ---------------------------------------------------------------------------
__global__ __launch_bounds__(256, 4)
void convKernel(const float* __restrict__ X, const float* __restrict__ Kw,
                const float* __restrict__ lnS, const float* __restrict__ lnB,
                const float* __restrict__ Mbuf, float* __restrict__ snn) {
  __shared__ int4   XS[8 * 65];       // [c2][row<63] fp16x8 rows; 8320 B
  __shared__ float4 hT4[512];         // [wid][cp][fq][tloc]; 8192 B; R alias

  const int bid  = blockIdx.x;        // 0..2303
  const int b    = bid / 36;
  const int tile = bid - b * 36;      // 0..35
  const int t0   = tile * 32;
  const int tid  = threadIdx.x;       // 0..255
  const int lane = tid & 63;
  const int wid  = tid >> 6;          // 0..3
  const int tcol = lane & 15;         // B col = local t
  const int rg   = lane >> 4;         // k-group; C/D rows rg*4+r
  const int fq   = rg & 1;            // f-quad of this lane's C/D rows
  const int tloc = tcol + ((rg >> 1) << 4);   // C/D local t (0..31)

  // ---- A-frags (K): rows 0-7 = f0-7 @ t, rows 8-15 = f0-7 @ t+16
  const int rA = lane & 15;
  const int fr = rA & 7;
  const int sh16 = (rA >> 3) << 4;
  f16x8 ka[12];
  #pragma unroll
  for (int q = 0; q < 12; ++q) {
    const int khs = 4 * q + rg - sh16;
    #pragma unroll
    for (int j = 0; j < 8; ++j) {
      float kv = (khs >= 0 && khs < 32) ? Kw[khs * 64 + j * 8 + fr] : 0.f;
      ka[q][j] = (_Float16)kv;
    }
  }

  // ---- per-thread LN/proj ids: 1 point (tpt, c2l=cslot) per part
  const int tpt   = lane >> 1;        // local t 0..31
  const int cslot = lane & 1;         // which of my wave's 2 channels

  // ---- staging geometry: 504 slots = 8 c2 x 63 rows; 2 per thread
  const int sc2 = tid & 7;
  const int srow0 = tid >> 3;         // 0..31
  const int srow1 = srow0 + 32;       // 32..63 (63 invalid)
  const int st0 = t0 - 15 + srow0;
  const int st1 = t0 - 15 + srow1;
  const bool v0 = (st0 >= 0) && (st0 < T_SEQ);
  const bool v1 = (srow1 < 63) && (st1 >= 0) && (st1 < T_SEQ);
  const float* xb = X + (size_t)(b * T_SEQ) * 512;

  float pacc[4][8];
  #pragma unroll
  for (int s = 0; s < 4; ++s)
    #pragma unroll
    for (int f = 0; f < 8; ++f) pacc[s][f] = 0.f;

  #pragma unroll 1
  for (int part = 0; part < 8; ++part) {
    // ---- stage X rows -> fp16 XS (direct)
    {
      const float* xp = xb + (part * 8 + sc2) * 8;
      float4 a0 = make_float4(0.f, 0.f, 0.f, 0.f), a1 = a0;
      float4 b0 = a0, b1 = a0;
      if (v0) { const float* p = xp + (size_t)st0 * 512; a0 = *(const float4*)p; a1 = *(const float4*)(p + 4); }
      if (v1) { const float* p = xp + (size_t)st1 * 512; b0 = *(const float4*)p; b1 = *(const float4*)(p + 4); }
      {
        unsigned u0 = __builtin_bit_cast(unsigned, __float22half2_rn(make_float2(a0.x, a0.y)));
        unsigned u1 = __builtin_bit_cast(unsigned, __float22half2_rn(make_float2(a0.z, a0.w)));
        unsigned u2 = __builtin_bit_cast(unsigned, __float22half2_rn(make_float2(a1.x, a1.y)));
        unsigned u3 = __builtin_bit_cast(unsigned, __float22half2_rn(make_float2(a1.z, a1.w)));
        int4 v; v.x = (int)u0; v.y = (int)u1; v.z = (int)u2; v.w = (int)u3;
        XS[sc2 * 65 + srow0] = v;
      }
      if (srow1 < 63) {
        unsigned u0 = __builtin_bit_cast(unsigned, __float22half2_rn(make_float2(b0.x, b0.y)));
        unsigned u1 = __builtin_bit_cast(unsigned, __float22half2_rn(make_float2(b0.z, b0.w)));
        unsigned u2 = __builtin_bit_cast(unsigned, __float22half2_rn(make_float2(b1.x, b1.y)));
        unsigned u3 = __builtin_bit_cast(unsigned, __float22half2_rn(make_float2(b1.z, b1.w)));
        int4 v; v.x = (int)u0; v.y = (int)u1; v.z = (int)u2; v.w = (int)u3;
        XS[sc2 * 65 + srow1] = v;
      }
    }
    __syncthreads();   // B1: XS ready

    // ---- MFMA: this wave's 2 c2; acc -> hT4 (wave-private, conflict-free)
    #pragma unroll
    for (int cp = 0; cp < 2; ++cp) {
      f32x4 acc = {0.f, 0.f, 0.f, 0.f};
      const int rb = (wid * 2 + cp) * 65 + tcol + rg;
      #pragma unroll
      for (int q = 0; q < 12; ++q) {
        f16x8 xf = __builtin_bit_cast(f16x8, XS[rb + 4 * q]);
        acc = __builtin_amdgcn_mfma_f32_16x16x32_f16(ka[q], xf, acc, 0, 0, 0);
      }
      float4 st; st.x = acc[0]; st.y = acc[1]; st.z = acc[2]; st.w = acc[3];
      hT4[wid * 128 + cp * 64 + fq * 32 + tloc] = st;
    }
    // wave-local lgkmcnt orders hT4 writes vs reads (compiler-inserted)

    // ---- per-thread LN + ReLU + proj: 1 point (tpt, cslot)
    {
      float4 lo = hT4[wid * 128 + cslot * 64 + tpt];
      float4 hi = hT4[wid * 128 + cslot * 64 + 32 + tpt];
      float hv[8] = { lo.x, lo.y, lo.z, lo.w, hi.x, hi.y, hi.z, hi.w };
      float mu = 0.f;
      #pragma unroll
      for (int f = 0; f < 8; ++f) mu += hv[f];
      mu *= 0.125f;
      float var = 0.f;
      #pragma unroll
      for (int f = 0; f < 8; ++f) { float d = hv[f] - mu; hv[f] = d; var = fmaf(d, d, var); }
      float rs = 1.0f / sqrtf(var * 0.125f + 1e-6f);
      const int c = part * 8 + wid * 2 + cslot;
      const float4 Mc = *(const float4*)(Mbuf + b * 256 + c * 4);
      #pragma unroll
      for (int f = 0; f < 8; ++f) {
        float hh = fmaxf(fmaf(hv[f] * rs, lnS[f], lnB[f]), 0.f);
        pacc[0][f] = fmaf(hh, Mc.x, pacc[0][f]);
        pacc[1][f] = fmaf(hh, Mc.y, pacc[1][f]);
        pacc[2][f] = fmaf(hh, Mc.z, pacc[2][f]);
        pacc[3][f] = fmaf(hh, Mc.w, pacc[3][f]);
      }
    }
    __syncthreads();   // B2: all XS/hT4 reads done before next part
  }

  // ---- epilogue: merge this wave's 2 channels (lane pairs), then 2-pass
  //      cross-wave sum through the hT4 region. FULLY UNROLLED so every
  //      pacc index is compile-time constant (v16's spill bug).
  #pragma unroll
  for (int s = 0; s < 4; ++s)
    #pragma unroll
    for (int f = 0; f < 8; ++f)
      pacc[s][f] += __shfl_xor(pacc[s][f], 1, 64);

  float* R = (float*)hT4;             // 2048 floats; per pass uses 1536
  #pragma unroll
  for (int pass = 0; pass < 2; ++pass) {
    __syncthreads();                  // prev-pass reads (or main loop) done
    if (wid > 0 && cslot == 0) {
      #pragma unroll
      for (int s2 = 0; s2 < 2; ++s2)
        #pragma unroll
        for (int f = 0; f < 8; ++f)
          R[((wid - 1) * 32 + tpt) * 16 + s2 * 8 + f] = pacc[pass * 2 + s2][f];
    }
    __syncthreads();
    if (wid == 0 && cslot == 0) {
      float* op = snn + ((size_t)b * T_SEQ + t0 + tpt) * 32;
      #pragma unroll
      for (int s2 = 0; s2 < 2; ++s2) {
        const int s = pass * 2 + s2;
        float v[8];
        #pragma unroll
        for (int f = 0; f < 8; ++f)
          v[f] = pacc[s][f]
               + R[(0 * 32 + tpt) * 16 + s2 * 8 + f]
               + R[(1 * 32 + tpt) * 16 + s2 * 8 + f]
               + R[(2 * 32 + tpt) * 16 + s2 * 8 + f];
        *(float4*)(op + s * 8)     = make_float4(v[0], v[1], v[2], v[3]);
        *(float4*)(op + s * 8 + 4) = make_float4(v[4], v[5], v[6], v[7]);
      }
    }
  }
}

// ---------------------------------------------------------------------------
// Kernel B: LIF scan — 1 chain/thread (32 blocks x 64 thr = 2048 chains),
// 24-deep ping-pong prefetch.
// ---------------------------------------------------------------------------
__global__ __launch_bounds__(64, 1)
void scanKernel(const float* __restrict__ snn, float* __restrict__ flat,
                float* __restrict__ spkPart) {
  const int tid = threadIdx.x;        // 0..63
  const int j = tid & 31;
  const int b = blockIdx.x * 2 + (tid >> 5);
  const float* base = snn + (size_t)b * T_SEQ * 32 + j;

  float m1 = 0.f, m2 = 0.f, mo = 0.f, s1 = 0.f, s2 = 0.f;
  float cur[24], nxt[24];
  #pragma unroll
  for (int u = 0; u < 24; ++u) cur[u] = base[(size_t)u * 32];

  #pragma unroll 1
  for (int ch = 0; ch < 48; ++ch) {
    if (ch < 47) {
      #pragma unroll
      for (int u = 0; u < 24; ++u) nxt[u] = base[(size_t)((ch + 1) * 24 + u) * 32];
    }
    float aS = 0.f, aE = 0.f;
    #pragma unroll
    for (int u = 0; u < 24; ++u) {
      m1 = m1 * 0.8f + cur[u];
      float sp1 = (m1 > 0.5f) ? 1.f : 0.f;  m1 -= sp1 * 0.5f;
      m2 = m2 * 0.9f + sp1;
      float sp2 = (m2 > 0.5f) ? 1.f : 0.f;  m2 -= sp2 * 0.5f;
      mo = mo * 0.95f + sp2;
      s1 += sp1; s2 += sp2;
      if (u < 12) aS += mo; else aE += mo;
    }
    flat[b * 3072 + ch * 64 + j]      = aS / 12.0f;
    flat[b * 3072 + ch * 64 + 32 + j] = aE / 12.0f;
    if (ch < 47) {
      #pragma unroll
      for (int u = 0; u < 24; ++u) cur[u] = nxt[u];
    }
  }
  for (int off = 16; off > 0; off >>= 1) {
    s1 += __shfl_down(s1, off, 32);
    s2 += __shfl_down(s2, off, 32);
  }
  if (j == 0) { spkPart[b * 2] = s1; spkPart[b * 2 + 1] = s2; }
}

// ---------------------------------------------------------------------------
// Kernel C: y = gelu(flat @ W1 + b1); logits = y @ W2 + b2 ; firing rate.
// ---------------------------------------------------------------------------
__global__ void mlpKernel(const float* __restrict__ flat, const float* __restrict__ W1,
                          const float* __restrict__ b1, const float* __restrict__ W2,
                          const float* __restrict__ b2, const float* __restrict__ spkPart,
                          float* __restrict__ out) {
  if (blockIdx.x == 64) {
    if (threadIdx.x == 0) {
      float s1 = 0.f, s2 = 0.f;
      for (int i = 0; i < 64; ++i) { s1 += spkPart[2*i]; s2 += spkPart[2*i+1]; }
      out[256] = (s1 + s2) * 0.5f / (64.0f * 1152.0f * 32.0f);
    }
    return;
  }
  const int b = blockIdx.x;
  const int tid = threadIdx.x;        // 256
  const int u = tid & 31, kc = tid >> 5;
  __shared__ float red[256];
  __shared__ float ys[32];
  float p = 0.f;
  const int kbeg = kc * 384, kend = kbeg + 384;
  #pragma unroll 4
  for (int k = kbeg; k < kend; ++k)
    p = fmaf(flat[b*3072 + k], W1[k*32 + u], p);
  red[tid] = p;
  __syncthreads();
  if (kc == 0) {
    float y = b1[u];
    #pragma unroll
    for (int q = 0; q < 8; ++q) y += red[q*32 + u];
    float y3 = y * y * y;
    float th = tanhf(0.7978845608028654f * (y + 0.044715f * y3));
    ys[u] = 0.5f * y * (1.0f + th);
  }
  __syncthreads();
  if (tid < 4) {
    float accv = b2[tid];
    #pragma unroll
    for (int q = 0; q < 32; ++q) accv = fmaf(ys[q], W2[q*4 + tid], accv);
    out[b*4 + tid] = accv;
  }
}

// ---------------------------------------------------------------------------
extern "C" void kernel_launch(void* const* d_in, const int* in_sizes, int n_in,
                              void* d_out, int out_size, void* d_ws, size_t ws_size,
                              hipStream_t stream) {
  const float* L   = (const float*)d_in[0];
  const float* X   = (const float*)d_in[1];
  // d_in[2] = deterministic (unused)
  const float* Kw  = (const float*)d_in[3];
  const float* lnS = (const float*)d_in[4];
  const float* lnB = (const float*)d_in[5];
  const float* sw  = (const float*)d_in[6];
  const float* W1  = (const float*)d_in[7];
  const float* b1  = (const float*)d_in[8];
  const float* W2  = (const float*)d_in[9];
  const float* b2  = (const float*)d_in[10];

  float* ws   = (float*)d_ws;
  float* Mbuf = ws;                       // 64*4*64    = 16384
  float* snn  = Mbuf + 16384;             // 64*1152*32 = 2359296
  float* flat = snn + 2359296;            // 64*3072    = 196608
  float* spk  = flat + 196608;            // 128
  float* out  = (float*)d_out;

  mKernel<<<64, 256, 0, stream>>>(L, sw, Mbuf);
  convKernel<<<2304, 256, 0, stream>>>(X, Kw, lnS, lnB, Mbuf, snn);
  scanKernel<<<32, 64, 0, stream>>>(snn, flat, spk);
  mlpKernel<<<65, 256, 0, stream>>>(flat, W1, b1, W2, b2, spk, out);
}

// Round 18
// 148.281 us; speedup vs baseline: 1.6390x; 1.0101x over previous
//
#include <hip/hip_runtime.h>
#include <hip/hip_fp16.h>
#include <math.h>

#define T_SEQ 1152

typedef _Float16 f16x8 __attribute__((ext_vector_type(8)));
typedef float f32x4 __attribute__((ext_vector_type(4)));

// ---------------------------------------------------------------------------
// Kernel 0: M[b,m,s] = sum_n spatial_w[n,s] * L_norm[b,n,m]  ([b][m][s] layout)
// ---------------------------------------------------------------------------
__global__ void mKernel(const float* __restrict__ L, const float* __restrict__ sw,
                        float* __restrict__ Mbuf) {
  int b = blockIdx.x, tid = threadIdx.x;   // 256 threads
  int s = tid >> 6, m = tid & 63;
  float a = 0.f;
  #pragma unroll 4
  for (int n = 0; n < 64; ++n)
    a = fmaf(sw[n * 4 + s], L[(b * 64 + n) * 64 + m], a);
  Mbuf[b * 256 + m * 4 + s] = a;
}

// ---------------------------------------------------------------------------
// Kernel A v18 = v17 + double-buffered XS, ONE barrier per part.
// Per part: issue part+1 loads into regs -> MFMA+LN/proj on XS[p&1] (covers
// the ~900cy HBM latency) -> convert+ds_write XS[(p+1)&1] -> barrier.
// Safety: reads of XS[p&1] complete before barrier p; the next writes to
// XS[p&1] happen in part p+1 after barrier p. Barriers 16 -> 8.
// t-tile 32, 2304 blocks; 4 waves cover the full 32-t tile, 2 c2/wave/part.
// GEMM: A = K (16 rows = 8f x {t,t+16} kh-shift), B = X (16 cols), 12 MFMA.
// LDS: XS 2x8.3KB + hT4 8KB = 24.8KB. Per-thread LN (no cross-lane per chan).
// Epilogue: shfl_xor(1) c-pair merge + 2-pass (unrolled) cross-wave sum.
// ---------------------------------------------------------------------------
__global__ __launch_bounds__(256, 4)
void convKernel(const float* __restrict__ X, const float* __restrict__ Kw,
                const float* __restrict__ lnS, const float* __restrict__ lnB,
                const float* __restrict__ Mbuf, float* __restrict__ snn) {
  __shared__ int4   XS[2][8 * 65];    // [buf][c2][row<63] fp16x8; 16640 B
  __shared__ float4 hT4[512];         // [wid][cp][fq][tloc]; 8192 B; R alias

  const int bid  = blockIdx.x;        // 0..2303
  const int b    = bid / 36;
  const int tile = bid - b * 36;      // 0..35
  const int t0   = tile * 32;
  const int tid  = threadIdx.x;       // 0..255
  const int lane = tid & 63;
  const int wid  = tid >> 6;          // 0..3
  const int tcol = lane & 15;         // B col = local t
  const int rg   = lane >> 4;         // k-group; C/D rows rg*4+r
  const int fq   = rg & 1;            // f-quad of this lane's C/D rows
  const int tloc = tcol + ((rg >> 1) << 4);   // C/D local t (0..31)

  // ---- A-frags (K): rows 0-7 = f0-7 @ t, rows 8-15 = f0-7 @ t+16
  const int rA = lane & 15;
  const int fr = rA & 7;
  const int sh16 = (rA >> 3) << 4;
  f16x8 ka[12];
  #pragma unroll
  for (int q = 0; q < 12; ++q) {
    const int khs = 4 * q + rg - sh16;
    #pragma unroll
    for (int j = 0; j < 8; ++j) {
      float kv = (khs >= 0 && khs < 32) ? Kw[khs * 64 + j * 8 + fr] : 0.f;
      ka[q][j] = (_Float16)kv;
    }
  }

  // ---- per-thread LN/proj ids: 1 point (tpt, c2l=cslot) per part
  const int tpt   = lane >> 1;        // local t 0..31
  const int cslot = lane & 1;         // which of my wave's 2 channels

  // ---- staging geometry: 504 slots = 8 c2 x 63 rows; 2 per thread
  const int sc2 = tid & 7;
  const int srow0 = tid >> 3;         // 0..31
  const int srow1 = srow0 + 32;       // 32..63 (63 invalid)
  const int st0 = t0 - 15 + srow0;
  const int st1 = t0 - 15 + srow1;
  const bool v0 = (st0 >= 0) && (st0 < T_SEQ);
  const bool v1 = (srow1 < 63) && (st1 >= 0) && (st1 < T_SEQ);
  const float* xb = X + (size_t)(b * T_SEQ) * 512;

  float pacc[4][8];
  #pragma unroll
  for (int s = 0; s < 4; ++s)
    #pragma unroll
    for (int f = 0; f < 8; ++f) pacc[s][f] = 0.f;

  const float4 z4 = make_float4(0.f, 0.f, 0.f, 0.f);

#define CVT_WRITE(BUF, P0, P1, Q0, Q1)                                       \
  { {                                                                        \
      unsigned u0 = __builtin_bit_cast(unsigned, __float22half2_rn(make_float2(P0.x, P0.y))); \
      unsigned u1 = __builtin_bit_cast(unsigned, __float22half2_rn(make_float2(P0.z, P0.w))); \
      unsigned u2 = __builtin_bit_cast(unsigned, __float22half2_rn(make_float2(P1.x, P1.y))); \
      unsigned u3 = __builtin_bit_cast(unsigned, __float22half2_rn(make_float2(P1.z, P1.w))); \
      int4 v; v.x = (int)u0; v.y = (int)u1; v.z = (int)u2; v.w = (int)u3;    \
      XS[BUF][sc2 * 65 + srow0] = v;                                         \
    }                                                                        \
    if (srow1 < 63) {                                                        \
      unsigned u0 = __builtin_bit_cast(unsigned, __float22half2_rn(make_float2(Q0.x, Q0.y))); \
      unsigned u1 = __builtin_bit_cast(unsigned, __float22half2_rn(make_float2(Q0.z, Q0.w))); \
      unsigned u2 = __builtin_bit_cast(unsigned, __float22half2_rn(make_float2(Q1.x, Q1.y))); \
      unsigned u3 = __builtin_bit_cast(unsigned, __float22half2_rn(make_float2(Q1.z, Q1.w))); \
      int4 v; v.x = (int)u0; v.y = (int)u1; v.z = (int)u2; v.w = (int)u3;    \
      XS[BUF][sc2 * 65 + srow1] = v;                                         \
    } }

  // ---- prologue: stage part 0 into XS[0]
  {
    const float* xp = xb + sc2 * 8;
    float4 a0 = z4, a1 = z4, b0 = z4, b1 = z4;
    if (v0) { const float* p = xp + (size_t)st0 * 512; a0 = *(const float4*)p; a1 = *(const float4*)(p + 4); }
    if (v1) { const float* p = xp + (size_t)st1 * 512; b0 = *(const float4*)p; b1 = *(const float4*)(p + 4); }
    CVT_WRITE(0, a0, a1, b0, b1)
  }
  __syncthreads();

  #pragma unroll 1
  for (int part = 0; part < 8; ++part) {
    // ---- issue next part's loads (latency hidden under MFMA+LN below)
    float4 pa0 = z4, pa1 = z4, pb0 = z4, pb1 = z4;
    if (part < 7) {
      const float* xp = xb + ((part + 1) * 8 + sc2) * 8;
      if (v0) { const float* p = xp + (size_t)st0 * 512; pa0 = *(const float4*)p; pa1 = *(const float4*)(p + 4); }
      if (v1) { const float* p = xp + (size_t)st1 * 512; pb0 = *(const float4*)p; pb1 = *(const float4*)(p + 4); }
    }

    // ---- MFMA: this wave's 2 c2 from XS[part&1]; acc -> hT4
    const int4* xsb = XS[part & 1];
    #pragma unroll
    for (int cp = 0; cp < 2; ++cp) {
      f32x4 acc = {0.f, 0.f, 0.f, 0.f};
      const int rb = (wid * 2 + cp) * 65 + tcol + rg;
      #pragma unroll
      for (int q = 0; q < 12; ++q) {
        f16x8 xf = __builtin_bit_cast(f16x8, xsb[rb + 4 * q]);
        acc = __builtin_amdgcn_mfma_f32_16x16x32_f16(ka[q], xf, acc, 0, 0, 0);
      }
      float4 st; st.x = acc[0]; st.y = acc[1]; st.z = acc[2]; st.w = acc[3];
      hT4[wid * 128 + cp * 64 + fq * 32 + tloc] = st;
    }
    // wave-local lgkmcnt orders hT4 writes vs reads (compiler-inserted)

    // ---- per-thread LN + ReLU + proj: 1 point (tpt, cslot)
    {
      float4 lo = hT4[wid * 128 + cslot * 64 + tpt];
      float4 hi = hT4[wid * 128 + cslot * 64 + 32 + tpt];
      float hv[8] = { lo.x, lo.y, lo.z, lo.w, hi.x, hi.y, hi.z, hi.w };
      float mu = 0.f;
      #pragma unroll
      for (int f = 0; f < 8; ++f) mu += hv[f];
      mu *= 0.125f;
      float var = 0.f;
      #pragma unroll
      for (int f = 0; f < 8; ++f) { float d = hv[f] - mu; hv[f] = d; var = fmaf(d, d, var); }
      float rs = 1.0f / sqrtf(var * 0.125f + 1e-6f);
      const int c = part * 8 + wid * 2 + cslot;
      const float4 Mc = *(const float4*)(Mbuf + b * 256 + c * 4);
      #pragma unroll
      for (int f = 0; f < 8; ++f) {
        float hh = fmaxf(fmaf(hv[f] * rs, lnS[f], lnB[f]), 0.f);
        pacc[0][f] = fmaf(hh, Mc.x, pacc[0][f]);
        pacc[1][f] = fmaf(hh, Mc.y, pacc[1][f]);
        pacc[2][f] = fmaf(hh, Mc.z, pacc[2][f]);
        pacc[3][f] = fmaf(hh, Mc.w, pacc[3][f]);
      }
    }

    // ---- write next buffer (vmcnt wait lands here, after ~1.5K cyc compute)
    if (part < 7) {
      CVT_WRITE((part + 1) & 1, pa0, pa1, pb0, pb1)
    }
    __syncthreads();   // single barrier per part
  }
#undef CVT_WRITE

  // ---- epilogue: merge this wave's 2 channels (lane pairs), then 2-pass
  //      cross-wave sum through the hT4 region (fully unrolled, rule #20).
  #pragma unroll
  for (int s = 0; s < 4; ++s)
    #pragma unroll
    for (int f = 0; f < 8; ++f)
      pacc[s][f] += __shfl_xor(pacc[s][f], 1, 64);

  float* R = (float*)hT4;             // 2048 floats; per pass uses 1536
  #pragma unroll
  for (int pass = 0; pass < 2; ++pass) {
    __syncthreads();                  // prev-pass reads (or main loop) done
    if (wid > 0 && cslot == 0) {
      #pragma unroll
      for (int s2 = 0; s2 < 2; ++s2)
        #pragma unroll
        for (int f = 0; f < 8; ++f)
          R[((wid - 1) * 32 + tpt) * 16 + s2 * 8 + f] = pacc[pass * 2 + s2][f];
    }
    __syncthreads();
    if (wid == 0 && cslot == 0) {
      float* op = snn + ((size_t)b * T_SEQ + t0 + tpt) * 32;
      #pragma unroll
      for (int s2 = 0; s2 < 2; ++s2) {
        const int s = pass * 2 + s2;
        float v[8];
        #pragma unroll
        for (int f = 0; f < 8; ++f)
          v[f] = pacc[s][f]
               + R[(0 * 32 + tpt) * 16 + s2 * 8 + f]
               + R[(1 * 32 + tpt) * 16 + s2 * 8 + f]
               + R[(2 * 32 + tpt) * 16 + s2 * 8 + f];
        *(float4*)(op + s * 8)     = make_float4(v[0], v[1], v[2], v[3]);
        *(float4*)(op + s * 8 + 4) = make_float4(v[4], v[5], v[6], v[7]);
      }
    }
  }
}

// ---------------------------------------------------------------------------
// Kernel B: LIF scan — 1 chain/thread (32 blocks x 64 thr = 2048 chains),
// 24-deep ping-pong prefetch.
// ---------------------------------------------------------------------------
__global__ __launch_bounds__(64, 1)
void scanKernel(const float* __restrict__ snn, float* __restrict__ flat,
                float* __restrict__ spkPart) {
  const int tid = threadIdx.x;        // 0..63
  const int j = tid & 31;
  const int b = blockIdx.x * 2 + (tid >> 5);
  const float* base = snn + (size_t)b * T_SEQ * 32 + j;

  float m1 = 0.f, m2 = 0.f, mo = 0.f, s1 = 0.f, s2 = 0.f;
  float cur[24], nxt[24];
  #pragma unroll
  for (int u = 0; u < 24; ++u) cur[u] = base[(size_t)u * 32];

  #pragma unroll 1
  for (int ch = 0; ch < 48; ++ch) {
    if (ch < 47) {
      #pragma unroll
      for (int u = 0; u < 24; ++u) nxt[u] = base[(size_t)((ch + 1) * 24 + u) * 32];
    }
    float aS = 0.f, aE = 0.f;
    #pragma unroll
    for (int u = 0; u < 24; ++u) {
      m1 = m1 * 0.8f + cur[u];
      float sp1 = (m1 > 0.5f) ? 1.f : 0.f;  m1 -= sp1 * 0.5f;
      m2 = m2 * 0.9f + sp1;
      float sp2 = (m2 > 0.5f) ? 1.f : 0.f;  m2 -= sp2 * 0.5f;
      mo = mo * 0.95f + sp2;
      s1 += sp1; s2 += sp2;
      if (u < 12) aS += mo; else aE += mo;
    }
    flat[b * 3072 + ch * 64 + j]      = aS / 12.0f;
    flat[b * 3072 + ch * 64 + 32 + j] = aE / 12.0f;
    if (ch < 47) {
      #pragma unroll
      for (int u = 0; u < 24; ++u) cur[u] = nxt[u];
    }
  }
  for (int off = 16; off > 0; off >>= 1) {
    s1 += __shfl_down(s1, off, 32);
    s2 += __shfl_down(s2, off, 32);
  }
  if (j == 0) { spkPart[b * 2] = s1; spkPart[b * 2 + 1] = s2; }
}

// ---------------------------------------------------------------------------
// Kernel C: y = gelu(flat @ W1 + b1); logits = y @ W2 + b2 ; firing rate.
// ---------------------------------------------------------------------------
__global__ void mlpKernel(const float* __restrict__ flat, const float* __restrict__ W1,
                          const float* __restrict__ b1, const float* __restrict__ W2,
                          const float* __restrict__ b2, const float* __restrict__ spkPart,
                          float* __restrict__ out) {
  if (blockIdx.x == 64) {
    if (threadIdx.x == 0) {
      float s1 = 0.f, s2 = 0.f;
      for (int i = 0; i < 64; ++i) { s1 += spkPart[2*i]; s2 += spkPart[2*i+1]; }
      out[256] = (s1 + s2) * 0.5f / (64.0f * 1152.0f * 32.0f);
    }
    return;
  }
  const int b = blockIdx.x;
  const int tid = threadIdx.x;        // 256
  const int u = tid & 31, kc = tid >> 5;
  __shared__ float red[256];
  __shared__ float ys[32];
  float p = 0.f;
  const int kbeg = kc * 384, kend = kbeg + 384;
  #pragma unroll 4
  for (int k = kbeg; k < kend; ++k)
    p = fmaf(flat[b*3072 + k], W1[k*32 + u], p);
  red[tid] = p;
  __syncthreads();
  if (kc == 0) {
    float y = b1[u];
    #pragma unroll
    for (int q = 0; q < 8; ++q) y += red[q*32 + u];
    float y3 = y * y * y;
    float th = tanhf(0.7978845608028654f * (y + 0.044715f * y3));
    ys[u] = 0.5f * y * (1.0f + th);
  }
  __syncthreads();
  if (tid < 4) {
    float accv = b2[tid];
    #pragma unroll
    for (int q = 0; q < 32; ++q) accv = fmaf(ys[q], W2[q*4 + tid], accv);
    out[b*4 + tid] = accv;
  }
}

// ---------------------------------------------------------------------------
extern "C" void kernel_launch(void* const* d_in, const int* in_sizes, int n_in,
                              void* d_out, int out_size, void* d_ws, size_t ws_size,
                              hipStream_t stream) {
  const float* L   = (const float*)d_in[0];
  const float* X   = (const float*)d_in[1];
  // d_in[2] = deterministic (unused)
  const float* Kw  = (const float*)d_in[3];
  const float* lnS = (const float*)d_in[4];
  const float* lnB = (const float*)d_in[5];
  const float* sw  = (const float*)d_in[6];
  const float* W1  = (const float*)d_in[7];
  const float* b1  = (const float*)d_in[8];
  const float* W2  = (const float*)d_in[9];
  const float* b2  = (const float*)d_in[10];

  float* ws   = (float*)d_ws;
  float* Mbuf = ws;                       // 64*4*64    = 16384
  float* snn  = Mbuf + 16384;             // 64*1152*32 = 2359296
  float* flat = snn + 2359296;            // 64*3072    = 196608
  float* spk  = flat + 196608;            // 128
  float* out  = (float*)d_out;

  mKernel<<<64, 256, 0, stream>>>(L, sw, Mbuf);
  convKernel<<<2304, 256, 0, stream>>>(X, Kw, lnS, lnB, Mbuf, snn);
  scanKernel<<<32, 64, 0, stream>>>(snn, flat, spk);
  mlpKernel<<<65, 256, 0, stream>>>(flat, W1, b1, W2, b2, spk, out);
}